// Round 2
// baseline (290.983 us; speedup 1.0000x reference)
//
#include <hip/hip_runtime.h>

#define TPB 256
#define MAXK 32

__global__ __launch_bounds__(TPB) void zbl_scatter(
    const float* __restrict__ rij,
    const float* __restrict__ rcov,
    const float* __restrict__ znum,
    const int*  __restrict__ fa,
    const int*  __restrict__ sa,
    const int*  __restrict__ types,
    float* __restrict__ partials,   // K copies of n_atoms floats
    int E, int nquad, int natoms, int K)
{
    // 16-entry (ti,tj) table, SoA: tab[f][t]. Each field's 16 entries span 16
    // distinct banks -> conflict-free random-entry reads.
    __shared__ float tab[9][16];
    if (threadIdx.x < 16) {
        const float cc[4] = {0.02817f, 0.28022f, 0.50986f, 0.18175f};
        const float dd[4] = {0.20162f, 0.4029f, 0.94229f, 3.1998f};
        const float COUL = 14.399645478425668f;
        int t = threadIdx.x;
        int ti = t >> 2, tj = t & 3;
        float zi = znum[ti], zj = znum[tj];
        float rc = rcov[ti] + rcov[tj];
        float a = 0.4685f / (powf(zi, 0.23f) + powf(zj, 0.23f));
        float inva = 1.0f / a;
        float factor = COUL * zi * zj;
        float da[4], ee[4];
        float phi = 0.0f, dphi = 0.0f, d2phi = 0.0f;
        #pragma unroll
        for (int k = 0; k < 4; ++k) {
            da[k] = dd[k] * inva;
            ee[k] = expf(-rc * da[k]);
            phi   += cc[k] * ee[k];
            dphi  -= cc[k] * da[k] * ee[k];
            d2phi += cc[k] * da[k] * da[k] * ee[k];
        }
        float invrc = 1.0f / rc;
        float ec   = factor * invrc * phi;
        float dec  = factor * invrc * (-phi * invrc + dphi);
        float d2ec = factor * invrc * (d2phi - 2.0f * invrc * dphi + 2.0f * phi * invrc * invrc);
        float A = (-3.0f * dec + rc * d2ec) * invrc * invrc;
        float B = (2.0f * dec - rc * d2ec) * invrc * invrc * invrc;
        float C = -ec + 0.5f * rc * dec - rc * rc * d2ec * (1.0f / 12.0f);
        const float L2E = 1.4426950408889634f;
        tab[0][t] = 0.5f * factor;      // folds final e/2
        tab[1][t] = rc;
        tab[2][t] = -da[0] * L2E;       // exp(-r*da) = exp2(r * (-da*log2e))
        tab[3][t] = -da[1] * L2E;
        tab[4][t] = -da[2] * L2E;
        tab[5][t] = -da[3] * L2E;
        tab[6][t] = A * (1.0f / 6.0f);
        tab[7][t] = B * 0.125f;
        tab[8][t] = C * 0.5f;
    }
    __syncthreads();

    const float cc0 = 0.02817f, cc1 = 0.28022f, cc2 = 0.50986f, cc3 = 0.18175f;
    // Block-private output copy: spreads atomic traffic over K x 12.5K lines.
    float* myout = partials + (size_t)(blockIdx.x % K) * natoms;

    int tid = blockIdx.x * TPB + threadIdx.x;

    if (tid < nquad) {
        const float4* rij4 = (const float4*)rij;
        const int4*   fa4  = (const int4*)fa;
        const int4*   sa4  = (const int4*)sa;
        float4 rv = rij4[tid];
        int4   iv = fa4[tid];
        int4   jv = sa4[tid];
        float ra[4] = {rv.x, rv.y, rv.z, rv.w};
        int   ia[4] = {iv.x, iv.y, iv.z, iv.w};
        int   ja[4] = {jv.x, jv.y, jv.z, jv.w};
        int   ta[4];
        #pragma unroll
        for (int k = 0; k < 4; ++k)
            ta[k] = types[ia[k]] * 4 + types[ja[k]];  // gathers issue early
        #pragma unroll
        for (int k = 0; k < 4; ++k) {
            int t = ta[k];
            float r = ra[k];
            if (r <= tab[1][t]) {
                float p = cc0 * __builtin_amdgcn_exp2f(r * tab[2][t])
                        + cc1 * __builtin_amdgcn_exp2f(r * tab[3][t])
                        + cc2 * __builtin_amdgcn_exp2f(r * tab[4][t])
                        + cc3 * __builtin_amdgcn_exp2f(r * tab[5][t]);
                float r3 = r * r * r;
                float poly = __builtin_fmaf(__builtin_fmaf(tab[7][t], r, tab[6][t]), r3, tab[8][t]);
                float e = __builtin_fmaf(tab[0][t] * p, __builtin_amdgcn_rcpf(r), poly);
                unsafeAtomicAdd(&myout[ia[k]], e);  // HW global_atomic_add_f32
            }
        }
    }

    // tail (E % 4 != 0)
    int base = nquad * 4;
    int tail = E - base;
    if (tid < tail) {
        int idx = base + tid;
        int i = fa[idx], j = sa[idx];
        int t = types[i] * 4 + types[j];
        float r = rij[idx];
        if (r <= tab[1][t]) {
            float p = cc0 * __builtin_amdgcn_exp2f(r * tab[2][t])
                    + cc1 * __builtin_amdgcn_exp2f(r * tab[3][t])
                    + cc2 * __builtin_amdgcn_exp2f(r * tab[4][t])
                    + cc3 * __builtin_amdgcn_exp2f(r * tab[5][t]);
            float r3 = r * r * r;
            float poly = __builtin_fmaf(__builtin_fmaf(tab[7][t], r, tab[6][t]), r3, tab[8][t]);
            float e = __builtin_fmaf(tab[0][t] * p, __builtin_amdgcn_rcpf(r), poly);
            unsafeAtomicAdd(&myout[i], e);
        }
    }
}

__global__ __launch_bounds__(TPB) void zbl_reduce(
    const float* __restrict__ partials,
    float* __restrict__ out,
    int natoms, int K)
{
    int i = blockIdx.x * TPB + threadIdx.x;
    if (i >= natoms) return;
    float s = 0.0f;
    for (int c = 0; c < K; ++c)
        s += partials[(size_t)c * natoms + i];  // coalesced per c
    out[i] = s;
}

extern "C" void kernel_launch(void* const* d_in, const int* in_sizes, int n_in,
                              void* d_out, int out_size, void* d_ws, size_t ws_size,
                              hipStream_t stream) {
    const float* rij  = (const float*)d_in[0];
    const float* rcov = (const float*)d_in[1];
    const float* znum = (const float*)d_in[2];
    const int*   fa   = (const int*)d_in[3];
    const int*   sa   = (const int*)d_in[4];
    const int*   types= (const int*)d_in[5];
    float* out = (float*)d_out;
    int E = in_sizes[0];
    int natoms = out_size;
    int nquad = E / 4;

    int K = (int)(ws_size / ((size_t)natoms * sizeof(float)));
    if (K > MAXK) K = MAXK;
    if (K < 1) K = 1;
    float* partials = (float*)d_ws;

    // zero the K partial copies (ws is re-poisoned 0xAA before every launch)
    hipMemsetAsync(d_ws, 0, (size_t)K * natoms * sizeof(float), stream);

    int tail = E - nquad * 4;
    int work = nquad > tail ? nquad : tail;
    int blocks = (work + TPB - 1) / TPB;
    if (blocks < 1) blocks = 1;
    zbl_scatter<<<blocks, TPB, 0, stream>>>(rij, rcov, znum, fa, sa, types,
                                            partials, E, nquad, natoms, K);

    int rblocks = (natoms + TPB - 1) / TPB;
    zbl_reduce<<<rblocks, TPB, 0, stream>>>(partials, out, natoms, K);
}

// Round 3
// 285.522 us; speedup vs baseline: 1.0191x; 1.0191x over previous
//
#include <hip/hip_runtime.h>

#define TPB_PACK 256
#define TPB_SCAT 1024
#define GRID_SCAT 512
#define TPB_RED 256
#define MAXK 8

// ---- pack atom types into 2 bits each: word w covers atoms [16w, 16w+15] ----
__global__ __launch_bounds__(TPB_PACK) void zbl_pack(
    const int* __restrict__ types, unsigned int* __restrict__ packed,
    int natoms, int nwords)
{
    int w = blockIdx.x * TPB_PACK + threadIdx.x;
    if (w >= nwords) return;
    int base = w << 4;
    unsigned int word = 0;
    #pragma unroll
    for (int j = 0; j < 16; ++j) {
        int i = base + j;
        unsigned int t = (i < natoms) ? (unsigned int)types[i] : 0u;
        word |= (t & 3u) << (2 * j);
    }
    packed[w] = word;
}

// ---- main scatter: LDS-cached type table, per-edge energy, atomic scatter ----
__global__ __launch_bounds__(TPB_SCAT) void zbl_scatter(
    const float* __restrict__ rij,
    const float* __restrict__ rcov,
    const float* __restrict__ znum,
    const int*  __restrict__ fa,
    const int*  __restrict__ sa,
    const unsigned int* __restrict__ packed,
    float* __restrict__ partials,   // K copies of natoms floats
    int E, int nquad, int natoms, int nwords, int K)
{
    extern __shared__ unsigned int s_packed[];   // nwords words (50 KB @200K atoms)
    __shared__ float tab[9][16];

    // stage the full 2-bit type table into LDS (coalesced, L2-resident)
    for (int w = threadIdx.x; w < nwords; w += TPB_SCAT)
        s_packed[w] = packed[w];

    if (threadIdx.x < 16) {
        const float cc[4] = {0.02817f, 0.28022f, 0.50986f, 0.18175f};
        const float dd[4] = {0.20162f, 0.4029f, 0.94229f, 3.1998f};
        const float COUL = 14.399645478425668f;
        int t = threadIdx.x;
        int ti = t >> 2, tj = t & 3;
        float zi = znum[ti], zj = znum[tj];
        float rc = rcov[ti] + rcov[tj];
        float a = 0.4685f / (powf(zi, 0.23f) + powf(zj, 0.23f));
        float inva = 1.0f / a;
        float factor = COUL * zi * zj;
        float da[4], ee[4];
        float phi = 0.0f, dphi = 0.0f, d2phi = 0.0f;
        #pragma unroll
        for (int k = 0; k < 4; ++k) {
            da[k] = dd[k] * inva;
            ee[k] = expf(-rc * da[k]);
            phi   += cc[k] * ee[k];
            dphi  -= cc[k] * da[k] * ee[k];
            d2phi += cc[k] * da[k] * da[k] * ee[k];
        }
        float invrc = 1.0f / rc;
        float ec   = factor * invrc * phi;
        float dec  = factor * invrc * (-phi * invrc + dphi);
        float d2ec = factor * invrc * (d2phi - 2.0f * invrc * dphi + 2.0f * phi * invrc * invrc);
        float A = (-3.0f * dec + rc * d2ec) * invrc * invrc;
        float B = (2.0f * dec - rc * d2ec) * invrc * invrc * invrc;
        float C = -ec + 0.5f * rc * dec - rc * rc * d2ec * (1.0f / 12.0f);
        const float L2E = 1.4426950408889634f;
        tab[0][t] = 0.5f * factor;      // folds final e/2
        tab[1][t] = rc;
        tab[2][t] = -da[0] * L2E;       // c*exp(-r*da) = exp2(r*slope + log2 c)
        tab[3][t] = -da[1] * L2E;
        tab[4][t] = -da[2] * L2E;
        tab[5][t] = -da[3] * L2E;
        tab[6][t] = A * (1.0f / 6.0f);
        tab[7][t] = B * 0.125f;
        tab[8][t] = C * 0.5f;
    }
    __syncthreads();

    // log2 of the ZBL c-coefficients (folded into exp2 args)
    const float lc0 = -5.1497481f;   // log2(0.02817)
    const float lc1 = -1.8353434f;   // log2(0.28022)
    const float lc2 = -0.9718340f;   // log2(0.50986)
    const float lc3 = -2.4600449f;   // log2(0.18175)

    float* myout = partials + (size_t)(blockIdx.x % K) * natoms;

    const float4* rij4 = (const float4*)rij;
    const int4*   fa4  = (const int4*)fa;
    const int4*   sa4  = (const int4*)sa;

    int tid0 = blockIdx.x * TPB_SCAT + threadIdx.x;
    int nth  = gridDim.x * TPB_SCAT;

    for (int q = tid0; q < nquad; q += nth) {
        float4 rv = rij4[q];
        int4   iv = fa4[q];
        int4   jv = sa4[q];
        float ra[4] = {rv.x, rv.y, rv.z, rv.w};
        int   ia[4] = {iv.x, iv.y, iv.z, iv.w};
        int   ja[4] = {jv.x, jv.y, jv.z, jv.w};
        int   ta[4];
        #pragma unroll
        for (int k = 0; k < 4; ++k) {
            int i = ia[k], j = ja[k];
            unsigned int wi = s_packed[i >> 4], wj = s_packed[j >> 4];
            unsigned int ti = (wi >> ((i & 15) * 2)) & 3u;
            unsigned int tj = (wj >> ((j & 15) * 2)) & 3u;
            ta[k] = (int)(ti * 4u + tj);
        }
        #pragma unroll
        for (int k = 0; k < 4; ++k) {
            int t = ta[k];
            float r = ra[k];
            if (r <= tab[1][t]) {
                float p = __builtin_amdgcn_exp2f(__builtin_fmaf(r, tab[2][t], lc0))
                        + __builtin_amdgcn_exp2f(__builtin_fmaf(r, tab[3][t], lc1))
                        + __builtin_amdgcn_exp2f(__builtin_fmaf(r, tab[4][t], lc2))
                        + __builtin_amdgcn_exp2f(__builtin_fmaf(r, tab[5][t], lc3));
                float r3 = r * r * r;
                float poly = __builtin_fmaf(__builtin_fmaf(tab[7][t], r, tab[6][t]), r3, tab[8][t]);
                float e = __builtin_fmaf(tab[0][t] * p, __builtin_amdgcn_rcpf(r), poly);
                unsafeAtomicAdd(&myout[ia[k]], e);
            }
        }
    }

    // tail (E % 4 != 0)
    int base = nquad * 4;
    for (int idx = base + tid0; idx < E; idx += nth) {
        int i = fa[idx], j = sa[idx];
        unsigned int wi = s_packed[i >> 4], wj = s_packed[j >> 4];
        int t = (int)((((wi >> ((i & 15) * 2)) & 3u) << 2) | ((wj >> ((j & 15) * 2)) & 3u));
        float r = rij[idx];
        if (r <= tab[1][t]) {
            float p = __builtin_amdgcn_exp2f(__builtin_fmaf(r, tab[2][t], lc0))
                    + __builtin_amdgcn_exp2f(__builtin_fmaf(r, tab[3][t], lc1))
                    + __builtin_amdgcn_exp2f(__builtin_fmaf(r, tab[4][t], lc2))
                    + __builtin_amdgcn_exp2f(__builtin_fmaf(r, tab[5][t], lc3));
            float r3 = r * r * r;
            float poly = __builtin_fmaf(__builtin_fmaf(tab[7][t], r, tab[6][t]), r3, tab[8][t]);
            float e = __builtin_fmaf(tab[0][t] * p, __builtin_amdgcn_rcpf(r), poly);
            unsafeAtomicAdd(&myout[i], e);
        }
    }
}

__global__ __launch_bounds__(TPB_RED) void zbl_reduce(
    const float* __restrict__ partials,
    float* __restrict__ out,
    int natoms, int K)
{
    int i = blockIdx.x * TPB_RED + threadIdx.x;
    if (i >= natoms) return;
    float s = 0.0f;
    for (int c = 0; c < K; ++c)
        s += partials[(size_t)c * natoms + i];
    out[i] = s;   // writes every element -> no d_out memset needed
}

extern "C" void kernel_launch(void* const* d_in, const int* in_sizes, int n_in,
                              void* d_out, int out_size, void* d_ws, size_t ws_size,
                              hipStream_t stream) {
    const float* rij  = (const float*)d_in[0];
    const float* rcov = (const float*)d_in[1];
    const float* znum = (const float*)d_in[2];
    const int*   fa   = (const int*)d_in[3];
    const int*   sa   = (const int*)d_in[4];
    const int*   types= (const int*)d_in[5];
    float* out = (float*)d_out;
    int E = in_sizes[0];
    int natoms = out_size;
    int nquad = E / 4;
    int nwords = (natoms + 15) / 16;

    // ws layout: [packed 2-bit table][K partial accumulators]
    unsigned int* packed = (unsigned int*)d_ws;
    size_t packed_bytes = ((size_t)nwords * 4 + 255) & ~(size_t)255;
    float* partials = (float*)((char*)d_ws + packed_bytes);
    int K = (int)((ws_size - packed_bytes) / ((size_t)natoms * sizeof(float)));
    if (K > MAXK) K = MAXK;
    if (K < 1) K = 1;

    zbl_pack<<<(nwords + TPB_PACK - 1) / TPB_PACK, TPB_PACK, 0, stream>>>(
        types, packed, natoms, nwords);

    hipMemsetAsync(partials, 0, (size_t)K * natoms * sizeof(float), stream);

    size_t smem = (size_t)nwords * sizeof(unsigned int);
    zbl_scatter<<<GRID_SCAT, TPB_SCAT, smem, stream>>>(
        rij, rcov, znum, fa, sa, packed, partials, E, nquad, natoms, nwords, K);

    zbl_reduce<<<(natoms + TPB_RED - 1) / TPB_RED, TPB_RED, 0, stream>>>(
        partials, out, natoms, K);
}

// Round 4
// 217.325 us; speedup vs baseline: 1.3389x; 1.3138x over previous
//
#include <hip/hip_runtime.h>

#define P1_BLOCKS 512
#define P1_TPB    512
#define BUCKET_BITS 10
#define BS (1 << BUCKET_BITS)        // atoms per bucket
#define P2_TPB    1024
#define CMAX      48
#define NB_MAX    256                 // LDS counter array bound

// ---------------- Phase 1: compute edge energies, bin records ----------------
__global__ __launch_bounds__(P1_TPB) void zbl_bin(
    const float* __restrict__ rij,
    const float* __restrict__ rcov,
    const float* __restrict__ znum,
    const int*  __restrict__ fa,
    const int*  __restrict__ sa,
    const int*  __restrict__ types,
    int2*  __restrict__ regions,     // [P1_BLOCKS][NB][C] records {e_bits, atom}
    int*   __restrict__ counts,      // [P1_BLOCKS][NB]
    float* __restrict__ fallback,    // natoms floats (pre-zeroed); = d_out if C==0
    int E, int nquad, int NB, int C, int chunkQ)
{
    __shared__ float tab[9][16];
    __shared__ int scnt[NB_MAX];

    for (int t = threadIdx.x; t < NB; t += P1_TPB) scnt[t] = 0;

    if (threadIdx.x < 16) {
        const float cc[4] = {0.02817f, 0.28022f, 0.50986f, 0.18175f};
        const float dd[4] = {0.20162f, 0.4029f, 0.94229f, 3.1998f};
        const float COUL = 14.399645478425668f;
        int t = threadIdx.x;
        int ti = t >> 2, tj = t & 3;
        float zi = znum[ti], zj = znum[tj];
        float rc = rcov[ti] + rcov[tj];
        float a = 0.4685f / (powf(zi, 0.23f) + powf(zj, 0.23f));
        float inva = 1.0f / a;
        float factor = COUL * zi * zj;
        float da[4], ee[4];
        float phi = 0.0f, dphi = 0.0f, d2phi = 0.0f;
        #pragma unroll
        for (int k = 0; k < 4; ++k) {
            da[k] = dd[k] * inva;
            ee[k] = expf(-rc * da[k]);
            phi   += cc[k] * ee[k];
            dphi  -= cc[k] * da[k] * ee[k];
            d2phi += cc[k] * da[k] * da[k] * ee[k];
        }
        float invrc = 1.0f / rc;
        float ec   = factor * invrc * phi;
        float dec  = factor * invrc * (-phi * invrc + dphi);
        float d2ec = factor * invrc * (d2phi - 2.0f * invrc * dphi + 2.0f * phi * invrc * invrc);
        float A = (-3.0f * dec + rc * d2ec) * invrc * invrc;
        float B = (2.0f * dec - rc * d2ec) * invrc * invrc * invrc;
        float Cc = -ec + 0.5f * rc * dec - rc * rc * d2ec * (1.0f / 12.0f);
        const float L2E = 1.4426950408889634f;
        tab[0][t] = 0.5f * factor;      // folds final e/2
        tab[1][t] = rc;
        tab[2][t] = -da[0] * L2E;       // c*exp(-r*da) = exp2(r*slope + log2 c)
        tab[3][t] = -da[1] * L2E;
        tab[4][t] = -da[2] * L2E;
        tab[5][t] = -da[3] * L2E;
        tab[6][t] = A * (1.0f / 6.0f);
        tab[7][t] = B * 0.125f;
        tab[8][t] = Cc * 0.5f;
    }
    __syncthreads();

    const float lc0 = -5.1497481f;   // log2(0.02817)
    const float lc1 = -1.8353434f;   // log2(0.28022)
    const float lc2 = -0.9718340f;   // log2(0.50986)
    const float lc3 = -2.4600449f;   // log2(0.18175)

    const float4* rij4 = (const float4*)rij;
    const int4*   fa4  = (const int4*)fa;
    const int4*   sa4  = (const int4*)sa;

    size_t regbase = (size_t)blockIdx.x * NB;

    int q0 = blockIdx.x * chunkQ;
    int q1 = q0 + chunkQ; if (q1 > nquad) q1 = nquad;

    for (int q = q0 + threadIdx.x; q < q1; q += P1_TPB) {
        float4 rv = rij4[q];
        int4   iv = fa4[q];
        int4   jv = sa4[q];
        float ra[4] = {rv.x, rv.y, rv.z, rv.w};
        int   ia[4] = {iv.x, iv.y, iv.z, iv.w};
        int   ja[4] = {jv.x, jv.y, jv.z, jv.w};
        int   ta[4];
        #pragma unroll
        for (int k = 0; k < 4; ++k)
            ta[k] = types[ia[k]] * 4 + types[ja[k]];   // gathers issue early (L2/L3-hit)
        #pragma unroll
        for (int k = 0; k < 4; ++k) {
            int t = ta[k];
            float r = ra[k];
            if (r <= tab[1][t]) {
                float p = __builtin_amdgcn_exp2f(__builtin_fmaf(r, tab[2][t], lc0))
                        + __builtin_amdgcn_exp2f(__builtin_fmaf(r, tab[3][t], lc1))
                        + __builtin_amdgcn_exp2f(__builtin_fmaf(r, tab[4][t], lc2))
                        + __builtin_amdgcn_exp2f(__builtin_fmaf(r, tab[5][t], lc3));
                float r3 = r * r * r;
                float poly = __builtin_fmaf(__builtin_fmaf(tab[7][t], r, tab[6][t]), r3, tab[8][t]);
                float e = __builtin_fmaf(tab[0][t] * p, __builtin_amdgcn_rcpf(r), poly);
                int atom = ia[k];
                int b = atom >> BUCKET_BITS;
                int slot = atomicAdd(&scnt[b], 1);     // LDS atomic, cheap
                if (slot < C)
                    regions[(regbase + b) * (size_t)C + slot] =
                        make_int2(__float_as_int(e), atom);
                else
                    unsafeAtomicAdd(&fallback[atom], e);  // rare overflow
            }
        }
    }

    // tail (E % 4 != 0) handled by block 0
    if (blockIdx.x == 0) {
        for (int idx = nquad * 4 + threadIdx.x; idx < E; idx += P1_TPB) {
            int i = fa[idx], j = sa[idx];
            int t = types[i] * 4 + types[j];
            float r = rij[idx];
            if (r <= tab[1][t]) {
                float p = __builtin_amdgcn_exp2f(__builtin_fmaf(r, tab[2][t], lc0))
                        + __builtin_amdgcn_exp2f(__builtin_fmaf(r, tab[3][t], lc1))
                        + __builtin_amdgcn_exp2f(__builtin_fmaf(r, tab[4][t], lc2))
                        + __builtin_amdgcn_exp2f(__builtin_fmaf(r, tab[5][t], lc3));
                float r3 = r * r * r;
                float poly = __builtin_fmaf(__builtin_fmaf(tab[7][t], r, tab[6][t]), r3, tab[8][t]);
                float e = __builtin_fmaf(tab[0][t] * p, __builtin_amdgcn_rcpf(r), poly);
                int b = i >> BUCKET_BITS;
                int slot = atomicAdd(&scnt[b], 1);
                if (slot < C)
                    regions[(regbase + b) * (size_t)C + slot] =
                        make_int2(__float_as_int(e), i);
                else
                    unsafeAtomicAdd(&fallback[i], e);
            }
        }
    }

    __syncthreads();
    if (C > 0)
        for (int t = threadIdx.x; t < NB; t += P1_TPB)
            counts[blockIdx.x * NB + t] = min(scnt[t], C);
}

// ---------------- Phase 2: per-bucket LDS aggregation ----------------
__global__ __launch_bounds__(P2_TPB) void zbl_agg(
    const int2* __restrict__ regions,
    const int*  __restrict__ counts,
    const float* __restrict__ fallback,
    float* __restrict__ out,
    int natoms, int NB, int C, int P)
{
    __shared__ float acc[BS];
    int b = blockIdx.x;
    for (int i = threadIdx.x; i < BS; i += P2_TPB) acc[i] = 0.0f;
    __syncthreads();

    int wave = threadIdx.x >> 6;
    int lane = threadIdx.x & 63;
    int nwaves = P2_TPB >> 6;
    for (int p = wave; p < P; p += nwaves) {
        int n = counts[p * NB + b];
        size_t base = ((size_t)p * NB + b) * (size_t)C;
        for (int t = lane; t < n; t += 64) {
            int2 r = regions[base + t];                 // coalesced
            atomicAdd(&acc[r.y & (BS - 1)], __int_as_float(r.x));  // ds_add_f32
        }
    }
    __syncthreads();

    int abase = b << BUCKET_BITS;
    for (int i = threadIdx.x; i < BS; i += P2_TPB) {
        int atom = abase + i;
        if (atom < natoms) out[atom] = acc[i] + fallback[atom];
    }
}

extern "C" void kernel_launch(void* const* d_in, const int* in_sizes, int n_in,
                              void* d_out, int out_size, void* d_ws, size_t ws_size,
                              hipStream_t stream) {
    const float* rij  = (const float*)d_in[0];
    const float* rcov = (const float*)d_in[1];
    const float* znum = (const float*)d_in[2];
    const int*   fa   = (const int*)d_in[3];
    const int*   sa   = (const int*)d_in[4];
    const int*   types= (const int*)d_in[5];
    float* out = (float*)d_out;
    int E = in_sizes[0];
    int natoms = out_size;
    int nquad = E / 4;
    int NB = (natoms + BS - 1) >> BUCKET_BITS;
    if (NB > NB_MAX) NB = NB_MAX;   // (natoms <= 256K with BS=1024)
    int chunkQ = (nquad + P1_BLOCKS - 1) / P1_BLOCKS;

    // ws layout: [regions P*NB*C*8][counts P*NB*4][fallback natoms*4]
    size_t fb_bytes = (size_t)natoms * 4;
    size_t cnt_bytes = (size_t)P1_BLOCKS * NB * 4;
    long long avail = (long long)ws_size - (long long)fb_bytes
                    - (long long)cnt_bytes - 4096;
    int C = 0;
    if (avail > 0) C = (int)(avail / ((long long)P1_BLOCKS * (long long)NB * 8));
    if (C > CMAX) C = CMAX;

    int2* regions = (int2*)d_ws;
    size_t reg_bytes = (size_t)P1_BLOCKS * NB * (size_t)C * 8;
    int*   counts   = (int*)((char*)d_ws + reg_bytes);
    float* fallback = (float*)((char*)d_ws + reg_bytes + cnt_bytes);

    if (C >= 1) {
        hipMemsetAsync(fallback, 0, fb_bytes, stream);
        zbl_bin<<<P1_BLOCKS, P1_TPB, 0, stream>>>(
            rij, rcov, znum, fa, sa, types, regions, counts, fallback,
            E, nquad, NB, C, chunkQ);
        zbl_agg<<<NB, P2_TPB, 0, stream>>>(
            regions, counts, fallback, out, natoms, NB, C, P1_BLOCKS);
    } else {
        // ws too small: pure-atomic fallback directly into out (correct, slow)
        hipMemsetAsync(d_out, 0, fb_bytes, stream);
        zbl_bin<<<P1_BLOCKS, P1_TPB, 0, stream>>>(
            rij, rcov, znum, fa, sa, types, regions, counts, out,
            E, nquad, NB, 0, chunkQ);
    }
}

// Round 5
// 188.808 us; speedup vs baseline: 1.5412x; 1.1510x over previous
//
#include <hip/hip_runtime.h>

#define TPB_PACK  256
#define P1_BLOCKS 512
#define P1_TPB    512
#define BUCKET_BITS 10
#define BS (1 << BUCKET_BITS)        // atoms per bucket
#define P2_TPB    256
#define P2_S      8                  // sub-blocks per bucket in phase 2
#define CMAX      64
#define NB_MAX    256

// ---- pack atom types into 2 bits each: word w covers atoms [16w, 16w+15] ----
__global__ __launch_bounds__(TPB_PACK) void zbl_pack(
    const int* __restrict__ types, unsigned int* __restrict__ packed,
    int natoms, int nwords)
{
    int w = blockIdx.x * TPB_PACK + threadIdx.x;
    if (w >= nwords) return;
    int base = w << 4;
    unsigned int word = 0;
    #pragma unroll
    for (int j = 0; j < 16; ++j) {
        int i = base + j;
        unsigned int t = (i < natoms) ? (unsigned int)types[i] : 0u;
        word |= (t & 3u) << (2 * j);
    }
    packed[w] = word;
}

// ------- Phase 1: LDS type table, compute edge energies, bin records -------
__global__ __launch_bounds__(P1_TPB) void zbl_bin(
    const float* __restrict__ rij,
    const float* __restrict__ rcov,
    const float* __restrict__ znum,
    const int*  __restrict__ fa,
    const int*  __restrict__ sa,
    const unsigned int* __restrict__ packed,
    int2*  __restrict__ regions,     // [P1_BLOCKS][NB][C] records {e_bits, atom}
    int*   __restrict__ counts,      // [NB][P1_BLOCKS]  (transposed!)
    float* __restrict__ fallback,    // natoms floats, pre-zeroed; = d_out if C==0
    int E, int nquad, int natoms, int nwords, int NB, int C, int chunkQ)
{
    extern __shared__ unsigned int s_packed[];   // nwords words (~50 KB)
    __shared__ float tab[9][16];
    __shared__ int scnt[NB_MAX];

    for (int w = threadIdx.x; w < nwords; w += P1_TPB)
        s_packed[w] = packed[w];                 // coalesced, L2/L3-resident
    for (int t = threadIdx.x; t < NB; t += P1_TPB) scnt[t] = 0;

    if (threadIdx.x < 16) {
        const float cc[4] = {0.02817f, 0.28022f, 0.50986f, 0.18175f};
        const float dd[4] = {0.20162f, 0.4029f, 0.94229f, 3.1998f};
        const float COUL = 14.399645478425668f;
        int t = threadIdx.x;
        int ti = t >> 2, tj = t & 3;
        float zi = znum[ti], zj = znum[tj];
        float rc = rcov[ti] + rcov[tj];
        float a = 0.4685f / (powf(zi, 0.23f) + powf(zj, 0.23f));
        float inva = 1.0f / a;
        float factor = COUL * zi * zj;
        float da[4], ee[4];
        float phi = 0.0f, dphi = 0.0f, d2phi = 0.0f;
        #pragma unroll
        for (int k = 0; k < 4; ++k) {
            da[k] = dd[k] * inva;
            ee[k] = expf(-rc * da[k]);
            phi   += cc[k] * ee[k];
            dphi  -= cc[k] * da[k] * ee[k];
            d2phi += cc[k] * da[k] * da[k] * ee[k];
        }
        float invrc = 1.0f / rc;
        float ec   = factor * invrc * phi;
        float dec  = factor * invrc * (-phi * invrc + dphi);
        float d2ec = factor * invrc * (d2phi - 2.0f * invrc * dphi + 2.0f * phi * invrc * invrc);
        float A = (-3.0f * dec + rc * d2ec) * invrc * invrc;
        float B = (2.0f * dec - rc * d2ec) * invrc * invrc * invrc;
        float Cc = -ec + 0.5f * rc * dec - rc * rc * d2ec * (1.0f / 12.0f);
        const float L2E = 1.4426950408889634f;
        tab[0][t] = 0.5f * factor;      // folds final e/2
        tab[1][t] = rc;
        tab[2][t] = -da[0] * L2E;       // c*exp(-r*da) = exp2(r*slope + log2 c)
        tab[3][t] = -da[1] * L2E;
        tab[4][t] = -da[2] * L2E;
        tab[5][t] = -da[3] * L2E;
        tab[6][t] = A * (1.0f / 6.0f);
        tab[7][t] = B * 0.125f;
        tab[8][t] = Cc * 0.5f;
    }
    __syncthreads();

    const float lc0 = -5.1497481f;   // log2(0.02817)
    const float lc1 = -1.8353434f;   // log2(0.28022)
    const float lc2 = -0.9718340f;   // log2(0.50986)
    const float lc3 = -2.4600449f;   // log2(0.18175)

    const float4* rij4 = (const float4*)rij;
    const int4*   fa4  = (const int4*)fa;
    const int4*   sa4  = (const int4*)sa;

    int q0 = blockIdx.x * chunkQ;
    int q1 = q0 + chunkQ; if (q1 > nquad) q1 = nquad;

    for (int q = q0 + threadIdx.x; q < q1; q += P1_TPB) {
        float4 rv = rij4[q];
        int4   iv = fa4[q];
        int4   jv = sa4[q];
        float ra[4] = {rv.x, rv.y, rv.z, rv.w};
        int   ia[4] = {iv.x, iv.y, iv.z, iv.w};
        int   ja[4] = {jv.x, jv.y, jv.z, jv.w};
        int   ta[4];
        #pragma unroll
        for (int k = 0; k < 4; ++k) {
            int i = ia[k], j = ja[k];
            unsigned int wi = s_packed[i >> 4], wj = s_packed[j >> 4];
            unsigned int ti = (wi >> ((i & 15) * 2)) & 3u;
            unsigned int tj = (wj >> ((j & 15) * 2)) & 3u;
            ta[k] = (int)((ti << 2) | tj);
        }
        #pragma unroll
        for (int k = 0; k < 4; ++k) {
            int t = ta[k];
            float r = ra[k];
            if (r <= tab[1][t]) {
                float p = __builtin_amdgcn_exp2f(__builtin_fmaf(r, tab[2][t], lc0))
                        + __builtin_amdgcn_exp2f(__builtin_fmaf(r, tab[3][t], lc1))
                        + __builtin_amdgcn_exp2f(__builtin_fmaf(r, tab[4][t], lc2))
                        + __builtin_amdgcn_exp2f(__builtin_fmaf(r, tab[5][t], lc3));
                float r3 = r * r * r;
                float poly = __builtin_fmaf(__builtin_fmaf(tab[7][t], r, tab[6][t]), r3, tab[8][t]);
                float e = __builtin_fmaf(tab[0][t] * p, __builtin_amdgcn_rcpf(r), poly);
                int atom = ia[k];
                int b = atom >> BUCKET_BITS;
                int slot = atomicAdd(&scnt[b], 1);     // LDS atomic
                if (slot < C)
                    regions[((size_t)blockIdx.x * NB + b) * (size_t)C + slot] =
                        make_int2(__float_as_int(e), atom);
                else
                    unsafeAtomicAdd(&fallback[atom], e);  // rare overflow
            }
        }
    }

    // tail (E % 4 != 0) handled by block 0
    if (blockIdx.x == 0) {
        for (int idx = nquad * 4 + threadIdx.x; idx < E; idx += P1_TPB) {
            int i = fa[idx], j = sa[idx];
            unsigned int wi = s_packed[i >> 4], wj = s_packed[j >> 4];
            int t = (int)((((wi >> ((i & 15) * 2)) & 3u) << 2) |
                           ((wj >> ((j & 15) * 2)) & 3u));
            float r = rij[idx];
            if (r <= tab[1][t]) {
                float p = __builtin_amdgcn_exp2f(__builtin_fmaf(r, tab[2][t], lc0))
                        + __builtin_amdgcn_exp2f(__builtin_fmaf(r, tab[3][t], lc1))
                        + __builtin_amdgcn_exp2f(__builtin_fmaf(r, tab[4][t], lc2))
                        + __builtin_amdgcn_exp2f(__builtin_fmaf(r, tab[5][t], lc3));
                float r3 = r * r * r;
                float poly = __builtin_fmaf(__builtin_fmaf(tab[7][t], r, tab[6][t]), r3, tab[8][t]);
                float e = __builtin_fmaf(tab[0][t] * p, __builtin_amdgcn_rcpf(r), poly);
                int b = i >> BUCKET_BITS;
                int slot = atomicAdd(&scnt[b], 1);
                if (slot < C)
                    regions[((size_t)blockIdx.x * NB + b) * (size_t)C + slot] =
                        make_int2(__float_as_int(e), i);
                else
                    unsafeAtomicAdd(&fallback[i], e);
            }
        }
    }

    __syncthreads();
    if (C > 0)
        for (int t = threadIdx.x; t < NB; t += P1_TPB)
            counts[t * P1_BLOCKS + blockIdx.x] = min(scnt[t], C);  // transposed
}

// ------- Phase 2: per-(bucket, sub-block) LDS aggregation, high parallelism -------
__global__ __launch_bounds__(P2_TPB) void zbl_agg(
    const int2* __restrict__ regions,
    const int*  __restrict__ counts,     // [NB][P1_BLOCKS]
    const float* __restrict__ fallback,
    float* __restrict__ out,             // pre-zeroed
    int natoms, int NB, int C)
{
    const int PPS = P1_BLOCKS / P2_S;    // producers per sub-block (64)
    __shared__ float acc[BS];
    __shared__ int s_n[PPS];

    int b = blockIdx.x;                  // bucket
    int s = blockIdx.y;                  // sub-block
    if (threadIdx.x < PPS)
        s_n[threadIdx.x] = counts[b * P1_BLOCKS + s + P2_S * threadIdx.x];
    for (int i = threadIdx.x; i < BS; i += P2_TPB) acc[i] = 0.0f;
    __syncthreads();

    int wave = threadIdx.x >> 6;
    int lane = threadIdx.x & 63;
    for (int pi = wave; pi < PPS; pi += (P2_TPB >> 6)) {
        int n = s_n[pi];                           // LDS, wave-uniform
        int p = s + P2_S * pi;
        if (lane < n) {                            // C <= 64: one wave pass
            int2 r = regions[((size_t)p * NB + b) * (size_t)C + lane];
            atomicAdd(&acc[r.y & (BS - 1)], __int_as_float(r.x));  // ds_add_f32
        }
    }
    __syncthreads();

    int abase = b << BUCKET_BITS;
    for (int i = threadIdx.x; i < BS; i += P2_TPB) {
        int atom = abase + i;
        if (atom < natoms) {
            float v = acc[i];
            if (s == 0) v += fallback[atom];       // add overflow exactly once
            unsafeAtomicAdd(&out[atom], v);        // coalesced lane-atomics
        }
    }
}

extern "C" void kernel_launch(void* const* d_in, const int* in_sizes, int n_in,
                              void* d_out, int out_size, void* d_ws, size_t ws_size,
                              hipStream_t stream) {
    const float* rij  = (const float*)d_in[0];
    const float* rcov = (const float*)d_in[1];
    const float* znum = (const float*)d_in[2];
    const int*   fa   = (const int*)d_in[3];
    const int*   sa   = (const int*)d_in[4];
    const int*   types= (const int*)d_in[5];
    float* out = (float*)d_out;
    int E = in_sizes[0];
    int natoms = out_size;
    int nquad = E / 4;
    int nwords = (natoms + 15) / 16;
    int NB = (natoms + BS - 1) >> BUCKET_BITS;
    if (NB > NB_MAX) NB = NB_MAX;
    int chunkQ = (nquad + P1_BLOCKS - 1) / P1_BLOCKS;

    // ws layout: [packed][counts][fallback][regions...]
    size_t packed_bytes = ((size_t)nwords * 4 + 255) & ~(size_t)255;
    size_t cnt_bytes    = ((size_t)NB * P1_BLOCKS * 4 + 255) & ~(size_t)255;
    size_t fb_bytes     = ((size_t)natoms * 4 + 255) & ~(size_t)255;
    unsigned int* packed = (unsigned int*)d_ws;
    int*   counts   = (int*)((char*)d_ws + packed_bytes);
    float* fallback = (float*)((char*)d_ws + packed_bytes + cnt_bytes);
    int2*  regions  = (int2*)((char*)d_ws + packed_bytes + cnt_bytes + fb_bytes);

    long long avail = (long long)ws_size - (long long)(packed_bytes + cnt_bytes + fb_bytes);
    int C = 0;
    if (avail > 0) C = (int)(avail / ((long long)P1_BLOCKS * (long long)NB * 8));
    if (C > CMAX) C = CMAX;

    size_t smem = (size_t)nwords * sizeof(unsigned int);

    zbl_pack<<<(nwords + TPB_PACK - 1) / TPB_PACK, TPB_PACK, 0, stream>>>(
        types, packed, natoms, nwords);

    if (C >= 1) {
        hipMemsetAsync(fallback, 0, fb_bytes, stream);
        hipMemsetAsync(d_out, 0, (size_t)natoms * 4, stream);
        zbl_bin<<<P1_BLOCKS, P1_TPB, smem, stream>>>(
            rij, rcov, znum, fa, sa, packed, regions, counts, fallback,
            E, nquad, natoms, nwords, NB, C, chunkQ);
        dim3 g2(NB, P2_S);
        zbl_agg<<<g2, P2_TPB, 0, stream>>>(
            regions, counts, fallback, out, natoms, NB, C);
    } else {
        // ws too small: pure-atomic path directly into out (correct, slow)
        hipMemsetAsync(d_out, 0, (size_t)natoms * 4, stream);
        zbl_bin<<<P1_BLOCKS, P1_TPB, smem, stream>>>(
            rij, rcov, znum, fa, sa, packed, regions, counts, out,
            E, nquad, natoms, nwords, NB, 0, chunkQ);
    }
}